// Round 8
// baseline (189.463 us; speedup 1.0000x reference)
//
#include <hip/hip_runtime.h>

// Problem constants (fixed by the reference setup_inputs)
#define N_PTS 8192   // points per batch
#define M_Q   2048   // query points per batch
#define C_F   64     // feature channels
#define NS    32     // nsample
#define B_SZ  8      // batch

// Native vector type for __builtin_nontemporal_store (HIP's float4 is a
// class type the builtin rejects; ext_vector_type has identical layout).
typedef float vfloat4 __attribute__((ext_vector_type(4)));

// ---------------------------------------------------------------------------
// K1: prep (unchanged since round 4, known-good).
//  blocks [0, 1024):   transpose feat (b,c,n) -> featT (b,n,c). 64x64 LDS
//                      tile, stride 65 (2-way bank = free).
//  blocks [1024, 1280): xyz4[b*N+n] = (x, y, z, p2sum), numpy f32 order,
//                      contract OFF — feeds the pinned d2 formula bit-for-bit.
// ---------------------------------------------------------------------------
__global__ __launch_bounds__(256) void prep_kernel(
    const float* __restrict__ feat, const float* __restrict__ xyz,
    float* __restrict__ featT, float4* __restrict__ xyz4)
{
#pragma clang fp contract(off)
    __shared__ float lds[C_F * 65];
    if (blockIdx.x < B_SZ * 128) {
        const int b  = blockIdx.x >> 7;        // 128 n-tiles per batch
        const int n0 = (blockIdx.x & 127) * 64;
        {
            const int c4 = threadIdx.x >> 6;   // 0..3
            const int nn = threadIdx.x & 63;
#pragma unroll
            for (int k = 0; k < 16; ++k) {
                const int c = k * 4 + c4;
                lds[c * 65 + nn] = feat[((size_t)b * C_F + c) * N_PTS + n0 + nn];
            }
        }
        __syncthreads();
        {
            const int n4 = threadIdx.x >> 6;   // 0..3
            const int c  = threadIdx.x & 63;
#pragma unroll
            for (int k = 0; k < 16; ++k) {
                const int nn = k * 4 + n4;
                featT[((size_t)b * N_PTS + n0 + nn) * C_F + c] = lds[c * 65 + nn];
            }
        }
    } else {
        const int i = (blockIdx.x - B_SZ * 128) * 256 + (int)threadIdx.x; // 0..B*N-1
        const float p0 = xyz[i * 3 + 0];
        const float p1 = xyz[i * 3 + 1];
        const float p2 = xyz[i * 3 + 2];
        const float s  = (p0 * p0 + p1 * p1) + p2 * p2;   // np.sum order, no fma
        xyz4[i] = make_float4(p0, p1, p2, s);
    }
}

// ---------------------------------------------------------------------------
// K2: fused ball-query + gather, v6: FULLY WAVE-DECOUPLED.
// Block = 4 waves = 4 queries; each wave scans AND gathers its own query
// with NO __syncthreads (sidx[w] is wave-private; same-wave LDS write->read
// ordering is lgkmcnt, compiler-inserted). Fast waves issue gather/store
// traffic while heavy-tail waves (full 8192-pt scan) are still scanning.
//
// Scan: round-4 exact. NUMERICS (pinned, rounds 2-6 passed absmax=0):
// d2 = (q2 + p2sum) - 2*qp, partials left-to-right f32, contract OFF.
//
// Gather (per wave): lane=(s4g 0..3, c4 0..15); 2 iters cover 8 sample-quads.
// Loads: fT[n*16+c4] — per inst 4 full 256B featT rows (amp 1.0).
// Register 4x4 transpose -> float4 stores: per inst 16 rows x one full 64B
// line. Stores are NONTEMPORAL (nt): output is write-once/never-read; keep
// the 140MB stream out of L2 so hot featT/xyz4 stay resident (4MiB/XCD).
// ---------------------------------------------------------------------------
__global__ __launch_bounds__(256) void qbg_kernel(
    const float4* __restrict__ xyz4, const float* __restrict__ nxyz,
    const float* __restrict__ featT, float* __restrict__ out)
{
#pragma clang fp contract(off)
    __shared__ int sidx[4][NS];

    const int lane = threadIdx.x & 63;
    const int w    = threadIdx.x >> 6;            // wave id 0..3
    const int q    = blockIdx.x * 4 + w;          // this wave's query
    const int b    = q >> 11;                     // M_Q = 2048
    const float4* __restrict__ xb = xyz4 + (size_t)b * N_PTS;

    // ---- scan phase (round-4 exact) ----
    {
        const float* __restrict__ qp = nxyz + (size_t)q * 3;
        const float qx = qp[0], qy = qp[1], qz = qp[2];
        const float q2 = (qx * qx + qy * qy) + qz * qz;   // np.sum order

        int  cnt = 0;
        int  first_idx = 0;
        bool have_first = false;

        for (int base = 0; base < N_PTS && cnt < NS; base += 256) {
            float4 P[4];
#pragma unroll
            for (int cc = 0; cc < 4; ++cc)
                P[cc] = xb[base + cc * 64 + lane];
#pragma unroll
            for (int cc = 0; cc < 4; ++cc) {
                if (cnt >= NS) break;                       // wave-uniform
                const float qpdot = (qx * P[cc].x + qy * P[cc].y) + qz * P[cc].z;
                const float d2 = (q2 + P[cc].w) - 2.0f * qpdot;   // ref formula
                const bool pred = d2 < 1.0f;
                const unsigned long long mask = __ballot(pred);
                if (mask) {
                    if (!have_first) {
                        first_idx = base + cc * 64 + __ffsll(mask) - 1;
                        have_first = true;
                    }
                    if (pred) {
                        const int pos = cnt + (int)__popcll(mask & ((1ull << lane) - 1ull));
                        if (pos < NS) sidx[w][pos] = base + cc * 64 + lane;
                    }
                    cnt += (int)__popcll(mask);
                }
            }
        }
        if (cnt < NS) {
            for (int p = cnt + lane; p < NS; p += 64) sidx[w][p] = first_idx;
        }
    }
    // NO barrier: sidx[w] is wave-private; same-wave LDS ordering suffices.

    // ---- gather phase: per-wave, register transpose, nt float4 stores ----
    const int c4  = lane & 15;                    // channel-quad 0..15
    const int s4g = lane >> 4;                    // 0..3
    const int mm  = q & (M_Q - 1);
    const size_t cstride = (size_t)M_Q * NS;      // 65536

    const float4* __restrict__ fT =
        (const float4*)(featT + (size_t)b * N_PTS * C_F);  // 16 float4 / point
    const float* __restrict__ xf = (const float*)xb;

#pragma unroll
    for (int it = 0; it < 2; ++it) {
        const int s4 = it * 4 + s4g;              // sample-quad 0..7

        const int n0 = sidx[w][s4 * 4 + 0];       // broadcast LDS reads
        const int n1 = sidx[w][s4 * 4 + 1];
        const int n2 = sidx[w][s4 * 4 + 2];
        const int n3 = sidx[w][s4 * 4 + 3];

        const float4 L0 = fT[(size_t)n0 * 16 + c4];
        const float4 L1 = fT[(size_t)n1 * 16 + c4];
        const float4 L2 = fT[(size_t)n2 * 16 + c4];
        const float4 L3 = fT[(size_t)n3 * 16 + c4];

        const size_t obase = ((size_t)b * 67 * M_Q + mm) * NS + s4 * 4;
        float* __restrict__ op = out + obase + (size_t)(3 + c4 * 4) * cstride;
        vfloat4 t0 = { L0.x, L1.x, L2.x, L3.x };
        vfloat4 t1 = { L0.y, L1.y, L2.y, L3.y };
        vfloat4 t2 = { L0.z, L1.z, L2.z, L3.z };
        vfloat4 t3 = { L0.w, L1.w, L2.w, L3.w };
        __builtin_nontemporal_store(t0, (vfloat4*)(op + 0 * cstride));
        __builtin_nontemporal_store(t1, (vfloat4*)(op + 1 * cstride));
        __builtin_nontemporal_store(t2, (vfloat4*)(op + 2 * cstride));
        __builtin_nontemporal_store(t3, (vfloat4*)(op + 3 * cstride));

        if (c4 < 3) {                             // xyz-diff rows 0..2
            const float qc = nxyz[q * 3 + c4];
            vfloat4 v;
            v.x = xf[n0 * 4 + c4] - qc;
            v.y = xf[n1 * 4 + c4] - qc;
            v.z = xf[n2 * 4 + c4] - qc;
            v.w = xf[n3 * 4 + c4] - qc;
            __builtin_nontemporal_store(v, (vfloat4*)(out + obase + (size_t)c4 * cstride));
        }
    }
}

extern "C" void kernel_launch(void* const* d_in, const int* in_sizes, int n_in,
                              void* d_out, int out_size, void* d_ws, size_t ws_size,
                              hipStream_t stream)
{
    const float* xyz  = (const float*)d_in[0];   // (B, N, 3)
    const float* nxyz = (const float*)d_in[1];   // (B, M, 3)
    const float* feat = (const float*)d_in[2];   // (B, C, N)
    float* out = (float*)d_out;                  // (B, 67, M, 32)

    float*  featT = (float*)d_ws;                             // 16.8 MB
    float4* xyz4  = (float4*)((char*)d_ws + (20 << 20));      // 1 MB

    const int Q = B_SZ * M_Q;                    // 16384 queries

    prep_kernel<<<B_SZ * 128 + (B_SZ * N_PTS) / 256, 256, 0, stream>>>(
        feat, xyz, featT, xyz4);
    qbg_kernel<<<Q / 4, 256, 0, stream>>>(xyz4, nxyz, featT, out);
}

// Round 9
// 184.959 us; speedup vs baseline: 1.0243x; 1.0243x over previous
//
#include <hip/hip_runtime.h>

// Problem constants (fixed by the reference setup_inputs)
#define N_PTS 8192   // points per batch
#define M_Q   2048   // query points per batch
#define C_F   64     // feature channels
#define NS    32     // nsample
#define B_SZ  8      // batch

// ---------------------------------------------------------------------------
// K1: prep (unchanged since round 4, known-good).
//  blocks [0, 1024):   transpose feat (b,c,n) -> featT (b,n,c). 64x64 LDS
//                      tile, stride 65 (2-way bank = free).
//  blocks [1024, 1280): xyz4[b*N+n] = (x, y, z, p2sum), numpy f32 order,
//                      contract OFF — feeds the pinned d2 formula bit-for-bit.
// ---------------------------------------------------------------------------
__global__ __launch_bounds__(256) void prep_kernel(
    const float* __restrict__ feat, const float* __restrict__ xyz,
    float* __restrict__ featT, float4* __restrict__ xyz4)
{
#pragma clang fp contract(off)
    __shared__ float lds[C_F * 65];
    if (blockIdx.x < B_SZ * 128) {
        const int b  = blockIdx.x >> 7;        // 128 n-tiles per batch
        const int n0 = (blockIdx.x & 127) * 64;
        {
            const int c4 = threadIdx.x >> 6;   // 0..3
            const int nn = threadIdx.x & 63;
#pragma unroll
            for (int k = 0; k < 16; ++k) {
                const int c = k * 4 + c4;
                lds[c * 65 + nn] = feat[((size_t)b * C_F + c) * N_PTS + n0 + nn];
            }
        }
        __syncthreads();
        {
            const int n4 = threadIdx.x >> 6;   // 0..3
            const int c  = threadIdx.x & 63;
#pragma unroll
            for (int k = 0; k < 16; ++k) {
                const int nn = k * 4 + n4;
                featT[((size_t)b * N_PTS + n0 + nn) * C_F + c] = lds[c * 65 + nn];
            }
        }
    } else {
        const int i = (blockIdx.x - B_SZ * 128) * 256 + (int)threadIdx.x; // 0..B*N-1
        const float p0 = xyz[i * 3 + 0];
        const float p1 = xyz[i * 3 + 1];
        const float p2 = xyz[i * 3 + 2];
        const float s  = (p0 * p0 + p1 * p1) + p2 * p2;   // np.sum order, no fma
        xyz4[i] = make_float4(p0, p1, p2, s);
    }
}

// ---------------------------------------------------------------------------
// K2: fused ball-query + gather, v7: BLOCK-COOPERATIVE 512B WRITE BURSTS.
// Block = 4 waves = 4 CONSECUTIVE-m queries.
//
// Scan (EXACT round-4 code; numerics pinned, rounds 2-8 passed absmax=0):
// d2 = (q2 + p2sum) - 2*qp, partials left-to-right f32, contract OFF.
//
// Gather v7: all 4 queries' output tile (67 rows x 128 samples) staged in
// LDS st[67][133] (pad 133: Phase-A scalar writes land 2-way/bank = free),
// then Phase B stores 2144 float4: per wave-inst 2 rows x 512B CONTIGUOUS.
// Rationale: every prior variant wrote <=128B per row before a 256KB jump
// (536 interleaved power-of-2-strided streams -> ~0% HBM page hits, all
// variants stuck at 1.7-2.3 TB/s). 4 consecutive m's per burst quadruples
// page locality toward the fill's 6.6 TB/s sequential behavior.
// ---------------------------------------------------------------------------
__global__ __launch_bounds__(256) void qbg_kernel(
    const float4* __restrict__ xyz4, const float* __restrict__ nxyz,
    const float* __restrict__ featT, float* __restrict__ out)
{
#pragma clang fp contract(off)
    __shared__ int   sidx[4][NS];
    __shared__ float st[67][133];                 // 35.6 KB

    const int lane = threadIdx.x & 63;
    const int w    = threadIdx.x >> 6;            // wave id 0..3
    const int q    = blockIdx.x * 4 + w;          // this wave's query
    const int b    = q >> 11;                     // M_Q = 2048
    const float4* __restrict__ xb = xyz4 + (size_t)b * N_PTS;

    // ---- scan phase (round-4 exact) ----
    {
        const float* __restrict__ qp = nxyz + (size_t)q * 3;
        const float qx = qp[0], qy = qp[1], qz = qp[2];
        const float q2 = (qx * qx + qy * qy) + qz * qz;   // np.sum order

        int  cnt = 0;
        int  first_idx = 0;
        bool have_first = false;

        for (int base = 0; base < N_PTS && cnt < NS; base += 256) {
            float4 P[4];
#pragma unroll
            for (int cc = 0; cc < 4; ++cc)
                P[cc] = xb[base + cc * 64 + lane];
#pragma unroll
            for (int cc = 0; cc < 4; ++cc) {
                if (cnt >= NS) break;                       // wave-uniform
                const float qpdot = (qx * P[cc].x + qy * P[cc].y) + qz * P[cc].z;
                const float d2 = (q2 + P[cc].w) - 2.0f * qpdot;   // ref formula
                const bool pred = d2 < 1.0f;
                const unsigned long long mask = __ballot(pred);
                if (mask) {
                    if (!have_first) {
                        first_idx = base + cc * 64 + __ffsll(mask) - 1;
                        have_first = true;
                    }
                    if (pred) {
                        const int pos = cnt + (int)__popcll(mask & ((1ull << lane) - 1ull));
                        if (pos < NS) sidx[w][pos] = base + cc * 64 + lane;
                    }
                    cnt += (int)__popcll(mask);
                }
            }
        }
        if (cnt < NS) {
            for (int p = cnt + lane; p < NS; p += 64) sidx[w][p] = first_idx;
        }
    }
    __syncthreads();

    // ---- Phase A: stage 4 queries x (3 xyz + 64 feat) x 32 samples ----
    {
        const int c4  = threadIdx.x & 15;         // channel-quad 0..15
        const int spl = threadIdx.x >> 4;         // 0..15
        const float4* __restrict__ fT =
            (const float4*)(featT + (size_t)b * N_PTS * C_F);
#pragma unroll
        for (int loop = 0; loop < 8; ++loop) {
            const int sp = loop * 16 + spl;       // sample-slot 0..127
            const int ql = sp >> 5;               // query slot 0..3
            const int s  = sp & 31;
            const int n  = sidx[ql][s];
            const float4 v = fT[(size_t)n * 16 + c4];
            st[3 + c4 * 4 + 0][sp] = v.x;
            st[3 + c4 * 4 + 1][sp] = v.y;
            st[3 + c4 * 4 + 2][sp] = v.z;
            st[3 + c4 * 4 + 3][sp] = v.w;
        }
        if (threadIdx.x < 128) {
            const int sp = threadIdx.x;
            const int ql = sp >> 5;
            const int s  = sp & 31;
            const int qq = blockIdx.x * 4 + ql;
            const int n  = sidx[ql][s];
            const float4 pv = xb[n];
            st[0][sp] = pv.x - nxyz[qq * 3 + 0];
            st[1][sp] = pv.y - nxyz[qq * 3 + 1];
            st[2][sp] = pv.z - nxyz[qq * 3 + 2];
        }
    }
    __syncthreads();

    // ---- Phase B: 2144 float4 stores; per wave-inst 2 rows x 512B contig ----
    {
        const int m0 = (blockIdx.x * 4) & (M_Q - 1);
        const size_t cstride = (size_t)M_Q * NS;  // 65536
        const size_t obase = (size_t)b * 67 * cstride + (size_t)m0 * NS;
#pragma unroll
        for (int it = 0; it < 9; ++it) {
            const int e = it * 256 + (int)threadIdx.x;
            if (e < 67 * 32) {                    // 2144 float4 total
                const int row = e >> 5;           // 0..66
                const int g   = e & 31;           // float4-group in 128-sample span
                float4 v;
                v.x = st[row][g * 4 + 0];
                v.y = st[row][g * 4 + 1];
                v.z = st[row][g * 4 + 2];
                v.w = st[row][g * 4 + 3];
                *(float4*)&out[obase + (size_t)row * cstride + g * 4] = v;
            }
        }
    }
}

extern "C" void kernel_launch(void* const* d_in, const int* in_sizes, int n_in,
                              void* d_out, int out_size, void* d_ws, size_t ws_size,
                              hipStream_t stream)
{
    const float* xyz  = (const float*)d_in[0];   // (B, N, 3)
    const float* nxyz = (const float*)d_in[1];   // (B, M, 3)
    const float* feat = (const float*)d_in[2];   // (B, C, N)
    float* out = (float*)d_out;                  // (B, 67, M, 32)

    float*  featT = (float*)d_ws;                             // 16.8 MB
    float4* xyz4  = (float4*)((char*)d_ws + (20 << 20));      // 1 MB

    const int Q = B_SZ * M_Q;                    // 16384 queries

    prep_kernel<<<B_SZ * 128 + (B_SZ * N_PTS) / 256, 256, 0, stream>>>(
        feat, xyz, featT, xyz4);
    qbg_kernel<<<Q / 4, 256, 0, stream>>>(xyz4, nxyz, featT, out);
}